// Round 3
// baseline (508.223 us; speedup 1.0000x reference)
//
#include <hip/hip_runtime.h>
#include <math.h>

#define IN_C 128
#define HID_C 64
#define OUT_C 40

// ---- grid-stride float4 zero ----
__global__ void zero_kernel(float4* __restrict__ p, long long n4) {
  long long i = (long long)blockIdx.x * blockDim.x + threadIdx.x;
  long long stride = (long long)gridDim.x * blockDim.x;
  for (; i < n4; i += stride) p[i] = make_float4(0.f, 0.f, 0.f, 0.f);
}

// ---- degree: count incoming edges (dst side) with int atomics ----
__global__ void deg_kernel(const int* __restrict__ dst, int E,
                           unsigned int* __restrict__ deg) {
  int i = blockIdx.x * blockDim.x + threadIdx.x;
  int stride = gridDim.x * blockDim.x;
  for (int e = i; e < E; e += stride) {
    atomicAdd(&deg[dst[e]], 1u);
  }
}

// ---- dinv[i] = rsqrt(deg[i] + 1)  (self-loop); in-place uint->float ----
__global__ void dinv_kernel(float* __restrict__ buf, int n) {
  int i = blockIdx.x * blockDim.x + threadIdx.x;
  if (i < n) {
    unsigned int d = ((unsigned int*)buf)[i];
    buf[i] = rsqrtf((float)d + 1.0f);
  }
}

// ---- y = x @ W1  (128 -> 64), 32 nodes per block, W1 in LDS ----
__global__ __launch_bounds__(256) void gemm1_kernel(
    const float* __restrict__ x, const float* __restrict__ W1,
    float* __restrict__ y, int n) {
  __shared__ float Ws[IN_C * HID_C];   // 32 KiB, [c][j]
  __shared__ float rows[4][IN_C];
  for (int t = threadIdx.x; t < IN_C * HID_C; t += 256) Ws[t] = W1[t];
  int g = threadIdx.x >> 6, lane = threadIdx.x & 63;
  int i0 = blockIdx.x * 32;
  for (int it = 0; it < 8; ++it) {
    int i = i0 + it * 4 + g;
    __syncthreads();             // covers Ws load on it==0, rows reuse after
    if (i < n) {
      size_t base = (size_t)i * IN_C;
      rows[g][lane]      = x[base + lane];
      rows[g][lane + 64] = x[base + lane + 64];
    }
    __syncthreads();
    if (i < n) {
      float a = 0.f;
#pragma unroll
      for (int c = 0; c < IN_C; ++c)
        a = fmaf(rows[g][c], Ws[c * HID_C + lane], a);
      y[(size_t)i * HID_C + lane] = a;
    }
  }
}

// ---- scatter 64ch: acc[dst] += dinv[src] * feat[src]; wave per edge ----
__global__ void scatter64_kernel(const int* __restrict__ eidx, int E,
                                 const float* __restrict__ feat,
                                 const float* __restrict__ dinv,
                                 float* __restrict__ acc) {
  int wave = (int)((blockIdx.x * blockDim.x + threadIdx.x) >> 6);
  int lane = threadIdx.x & 63;
  int nwaves = (int)((gridDim.x * blockDim.x) >> 6);
  for (int e = wave; e < E; e += nwaves) {
    int s = eidx[e];
    int d = eidx[E + e];
    float v = feat[(size_t)s * HID_C + lane] * dinv[s];
    unsafeAtomicAdd(acc + (size_t)d * HID_C + lane, v);
  }
}

// ---- finish1 (in place): y <- relu(dinv*(acc + dinv*y) + b1) ----
__global__ void finish1_kernel(float* __restrict__ y,
                               const float* __restrict__ acc,
                               const float* __restrict__ dinv,
                               const float* __restrict__ b1, long long total) {
  long long idx = (long long)blockIdx.x * blockDim.x + threadIdx.x;
  long long stride = (long long)gridDim.x * blockDim.x;
  for (; idx < total; idx += stride) {
    int i = (int)(idx >> 6);  // HID_C == 64
    int j = (int)(idx & 63);
    float di = dinv[i];
    float a = di * (acc[idx] + di * y[idx]) + b1[j];
    y[idx] = a > 0.f ? a : 0.f;
  }
}

// ---- z = h @ W2  (64 -> 40), 32 nodes per block ----
__global__ __launch_bounds__(256) void gemm2_kernel(
    const float* __restrict__ h, const float* __restrict__ W2,
    float* __restrict__ z, int n) {
  __shared__ float Ws[HID_C * OUT_C];  // 10 KiB
  __shared__ float rows[4][HID_C];
  for (int t = threadIdx.x; t < HID_C * OUT_C; t += 256) Ws[t] = W2[t];
  int g = threadIdx.x >> 6, lane = threadIdx.x & 63;
  int i0 = blockIdx.x * 32;
  for (int it = 0; it < 8; ++it) {
    int i = i0 + it * 4 + g;
    __syncthreads();
    if (i < n) rows[g][lane] = h[(size_t)i * HID_C + lane];
    __syncthreads();
    if (i < n && lane < OUT_C) {
      float a = 0.f;
#pragma unroll
      for (int c = 0; c < HID_C; ++c)
        a = fmaf(rows[g][c], Ws[c * OUT_C + lane], a);
      z[(size_t)i * OUT_C + lane] = a;
    }
  }
}

// ---- scatter 40ch: acc[dst] += dinv[src] * z[src]; wave per edge ----
__global__ void scatter40_kernel(const int* __restrict__ eidx, int E,
                                 const float* __restrict__ z,
                                 const float* __restrict__ dinv,
                                 float* __restrict__ acc) {
  int wave = (int)((blockIdx.x * blockDim.x + threadIdx.x) >> 6);
  int lane = threadIdx.x & 63;
  int nwaves = (int)((gridDim.x * blockDim.x) >> 6);
  for (int e = wave; e < E; e += nwaves) {
    int s = eidx[e];
    int d = eidx[E + e];
    float ds = dinv[s];
    if (lane < OUT_C) {
      float v = z[(size_t)s * OUT_C + lane] * ds;
      unsafeAtomicAdd(acc + (size_t)d * OUT_C + lane, v);
    }
  }
}

// ---- finish2: o = dinv*(acc + dinv*z) + b2; out = log_softmax(o) ----
__global__ __launch_bounds__(256) void finish2_kernel(
    const float* __restrict__ z, const float* __restrict__ acc,
    const float* __restrict__ dinv, const float* __restrict__ b2,
    float* __restrict__ out, int n) {
  int g = threadIdx.x >> 6, lane = threadIdx.x & 63;
  int i = blockIdx.x * 4 + g;
  if (i >= n) return;
  float o = -INFINITY;
  if (lane < OUT_C) {
    float di = dinv[i];
    size_t base = (size_t)i * OUT_C + lane;
    o = di * (acc[base] + di * z[base]) + b2[lane];
  }
  float m = o;
  for (int off = 32; off; off >>= 1) m = fmaxf(m, __shfl_xor(m, off));
  float ex = (lane < OUT_C) ? expf(o - m) : 0.f;
  float s = ex;
  for (int off = 32; off; off >>= 1) s += __shfl_xor(s, off);
  if (lane < OUT_C) out[(size_t)i * OUT_C + lane] = o - m - logf(s);
}

extern "C" void kernel_launch(void* const* d_in, const int* in_sizes, int n_in,
                              void* d_out, int out_size, void* d_ws, size_t ws_size,
                              hipStream_t stream) {
  const float* x   = (const float*)d_in[0];
  const int* eidx  = (const int*)d_in[1];   // harness delivers integers as int32
  const float* W1  = (const float*)d_in[2];
  const float* b1  = (const float*)d_in[3];
  const float* W2  = (const float*)d_in[4];
  const float* b2  = (const float*)d_in[5];
  float* out = (float*)d_out;

  int n = in_sizes[0] / IN_C;
  int E = in_sizes[1] / 2;

  size_t npad = ((size_t)n + 255) & ~(size_t)255;
  size_t fA = (size_t)n * HID_C;           // bufA elements used
  size_t fB = (size_t)n * HID_C;           // bufB elements used
  size_t needed = (npad + fA + fB) * sizeof(float);
  if (ws_size < needed) return;  // fail via absmax, not via GPU fault

  float* ws   = (float*)d_ws;
  float* dinv = ws;                 // [npad]  (uint deg counts, then dinv)
  float* bufA = ws + npad;          // y -> h (in place) -> acc2
  float* bufB = bufA + fA;          // acc1 -> z

  // degree + dinv
  zero_kernel<<<256, 256, 0, stream>>>((float4*)dinv, (long long)(npad / 4));
  deg_kernel<<<1024, 256, 0, stream>>>(eidx + E, E, (unsigned int*)dinv);
  dinv_kernel<<<(n + 255) / 256, 256, 0, stream>>>(dinv, n);

  // layer 1: y = x@W1 ; acc1 = scatter(y) ; h = relu(dinv*(acc1+dinv*y)+b1)
  gemm1_kernel<<<(n + 31) / 32, 256, 0, stream>>>(x, W1, bufA, n);
  zero_kernel<<<2048, 256, 0, stream>>>((float4*)bufB, (long long)(fB / 4));
  scatter64_kernel<<<8192, 256, 0, stream>>>(eidx, E, bufA, dinv, bufB);
  finish1_kernel<<<2048, 256, 0, stream>>>(bufA, bufB, dinv, b1,
                                           (long long)n * HID_C);

  // layer 2: z = h@W2 ; acc2 = scatter(z) ; out = logsoftmax(dinv*(acc2+dinv*z)+b2)
  gemm2_kernel<<<(n + 31) / 32, 256, 0, stream>>>(bufA, W2, bufB, n);
  zero_kernel<<<2048, 256, 0, stream>>>((float4*)bufA,
                                        (long long)(((size_t)n * OUT_C) / 4));
  scatter40_kernel<<<8192, 256, 0, stream>>>(eidx, E, bufB, dinv, bufA);
  finish2_kernel<<<(n + 3) / 4, 256, 0, stream>>>(bufB, bufA, dinv, b2, out, n);
}

// Round 4
// 337.124 us; speedup vs baseline: 1.5075x; 1.5075x over previous
//
#include <hip/hip_runtime.h>
#include <math.h>

#define IN_C 128
#define HID_C 64
#define OUT_C 40

// ---- grid-stride int4 zero ----
__global__ void zero4_kernel(int4* __restrict__ p, long long n4) {
  long long i = (long long)blockIdx.x * blockDim.x + threadIdx.x;
  long long stride = (long long)gridDim.x * blockDim.x;
  for (; i < n4; i += stride) p[i] = make_int4(0, 0, 0, 0);
}

// ---- degree: count incoming edges (dst side), int atomics ----
__global__ void deg_kernel(const int* __restrict__ dst, int E,
                           int* __restrict__ deg) {
  int i = blockIdx.x * blockDim.x + threadIdx.x;
  int stride = gridDim.x * blockDim.x;
  for (int e = i; e < E; e += stride) atomicAdd(&deg[dst[e]], 1);
}

// ---- dinv[i] = rsqrt(deg[i] + 1)  (self-loop) ----
__global__ void dinv_kernel(const int* __restrict__ deg,
                            float* __restrict__ dinv, int n) {
  int i = blockIdx.x * blockDim.x + threadIdx.x;
  if (i < n) dinv[i] = rsqrtf((float)deg[i] + 1.0f);
}

// ---- scan stage 1: per-1024-chunk inclusive scan + chunk totals ----
__global__ __launch_bounds__(256) void scan1_kernel(
    const int* __restrict__ deg, int* __restrict__ S, int* __restrict__ BS,
    int n) {
  __shared__ int sums[256];
  int t = threadIdx.x;
  int i0 = blockIdx.x * 1024 + t * 4;
  int v0 = (i0 + 0 < n) ? deg[i0 + 0] : 0;
  int v1 = (i0 + 1 < n) ? deg[i0 + 1] : 0;
  int v2 = (i0 + 2 < n) ? deg[i0 + 2] : 0;
  int v3 = (i0 + 3 < n) ? deg[i0 + 3] : 0;
  v1 += v0; v2 += v1; v3 += v2;
  sums[t] = v3;
  __syncthreads();
  for (int off = 1; off < 256; off <<= 1) {
    int x = (t >= off) ? sums[t - off] : 0;
    __syncthreads();
    sums[t] += x;
    __syncthreads();
  }
  int excl = t ? sums[t - 1] : 0;
  if (i0 + 0 < n) S[i0 + 0] = v0 + excl;
  if (i0 + 1 < n) S[i0 + 1] = v1 + excl;
  if (i0 + 2 < n) S[i0 + 2] = v2 + excl;
  if (i0 + 3 < n) S[i0 + 3] = v3 + excl;
  if (t == 255) BS[blockIdx.x] = sums[255];
}

// ---- scan stage 2: exclusive scan of chunk totals (nb <= 128) ----
__global__ __launch_bounds__(128) void scan2_kernel(int* __restrict__ BS,
                                                    int nb) {
  __shared__ int s[128];
  int t = threadIdx.x;
  s[t] = (t < nb) ? BS[t] : 0;
  __syncthreads();
  for (int off = 1; off < 128; off <<= 1) {
    int x = (t >= off) ? s[t - off] : 0;
    __syncthreads();
    s[t] += x;
    __syncthreads();
  }
  if (t < nb) BS[t] = t ? s[t - 1] : 0;
}

// ---- scan stage 3: rowptr + cursor ----
__global__ void scan3_kernel(const int* __restrict__ S,
                             const int* __restrict__ BS,
                             const int* __restrict__ deg,
                             int* __restrict__ rowptr,
                             int* __restrict__ cursor, int n) {
  int i = blockIdx.x * blockDim.x + threadIdx.x;
  if (i < n) {
    int r = S[i] + BS[i >> 10];      // inclusive prefix = rowptr[i+1]
    rowptr[i + 1] = r;
    cursor[i] = r - deg[i];          // = rowptr[i]
    if (i == 0) rowptr[0] = 0;
  }
}

// ---- CSR fill: bucket src indices by dst ----
__global__ void fill_kernel(const int* __restrict__ eidx, int E,
                            int* __restrict__ cursor, int* __restrict__ csr) {
  int i = blockIdx.x * blockDim.x + threadIdx.x;
  int stride = gridDim.x * blockDim.x;
  for (int e = i; e < E; e += stride) {
    int s = eidx[e];
    int d = eidx[E + e];
    int pos = atomicAdd(&cursor[d], 1);
    csr[pos] = s;
  }
}

// ---- y = x @ W1  (128 -> 64), 32 nodes per block, W1 in LDS ----
__global__ __launch_bounds__(256) void gemm1_kernel(
    const float* __restrict__ x, const float* __restrict__ W1,
    float* __restrict__ y, int n) {
  __shared__ float Ws[IN_C * HID_C];   // 32 KiB, [c][j]
  __shared__ float rows[4][IN_C];
  for (int t = threadIdx.x; t < IN_C * HID_C; t += 256) Ws[t] = W1[t];
  int g = threadIdx.x >> 6, lane = threadIdx.x & 63;
  int i0 = blockIdx.x * 32;
  for (int it = 0; it < 8; ++it) {
    int i = i0 + it * 4 + g;
    __syncthreads();
    if (i < n) {
      size_t base = (size_t)i * IN_C;
      rows[g][lane]      = x[base + lane];
      rows[g][lane + 64] = x[base + lane + 64];
    }
    __syncthreads();
    if (i < n) {
      float a = 0.f;
#pragma unroll
      for (int c = 0; c < IN_C; ++c)
        a = fmaf(rows[g][c], Ws[c * HID_C + lane], a);
      y[(size_t)i * HID_C + lane] = a;
    }
  }
}

// ---- gather 64ch + bias + ReLU: wave per node, lane = channel ----
__global__ __launch_bounds__(256) void gather64_kernel(
    const float* __restrict__ y, const int* __restrict__ rowptr,
    const int* __restrict__ csr, const float* __restrict__ dinv,
    const float* __restrict__ b1, float* __restrict__ h, int n) {
  int lane = threadIdx.x & 63;
  int i = (int)((blockIdx.x * blockDim.x + threadIdx.x) >> 6);
  if (i >= n) return;
  float di = dinv[i];
  float a = di * y[(size_t)i * HID_C + lane];   // self term (di^2 after final mul)
  int e = rowptr[i], end = rowptr[i + 1];
  for (; e + 3 < end; e += 4) {
    int s0 = csr[e], s1 = csr[e + 1], s2 = csr[e + 2], s3 = csr[e + 3];
    float a0 = dinv[s0] * y[(size_t)s0 * HID_C + lane];
    float a1 = dinv[s1] * y[(size_t)s1 * HID_C + lane];
    float a2 = dinv[s2] * y[(size_t)s2 * HID_C + lane];
    float a3 = dinv[s3] * y[(size_t)s3 * HID_C + lane];
    a += (a0 + a1) + (a2 + a3);
  }
  for (; e < end; ++e) {
    int s = csr[e];
    a += dinv[s] * y[(size_t)s * HID_C + lane];
  }
  float hv = di * a + b1[lane];
  h[(size_t)i * HID_C + lane] = hv > 0.f ? hv : 0.f;
}

// ---- z = h @ W2  (64 -> 40), 32 nodes per block ----
__global__ __launch_bounds__(256) void gemm2_kernel(
    const float* __restrict__ h, const float* __restrict__ W2,
    float* __restrict__ z, int n) {
  __shared__ float Ws[HID_C * OUT_C];  // 10 KiB
  __shared__ float rows[4][HID_C];
  for (int t = threadIdx.x; t < HID_C * OUT_C; t += 256) Ws[t] = W2[t];
  int g = threadIdx.x >> 6, lane = threadIdx.x & 63;
  int i0 = blockIdx.x * 32;
  for (int it = 0; it < 8; ++it) {
    int i = i0 + it * 4 + g;
    __syncthreads();
    if (i < n) rows[g][lane] = h[(size_t)i * HID_C + lane];
    __syncthreads();
    if (i < n && lane < OUT_C) {
      float a = 0.f;
#pragma unroll
      for (int c = 0; c < HID_C; ++c)
        a = fmaf(rows[g][c], Ws[c * OUT_C + lane], a);
      z[(size_t)i * OUT_C + lane] = a;
    }
  }
}

// ---- gather 40ch + bias + log-softmax: wave per node ----
__global__ __launch_bounds__(256) void gather40_kernel(
    const float* __restrict__ z, const int* __restrict__ rowptr,
    const int* __restrict__ csr, const float* __restrict__ dinv,
    const float* __restrict__ b2, float* __restrict__ out, int n) {
  int lane = threadIdx.x & 63;
  int i = (int)((blockIdx.x * blockDim.x + threadIdx.x) >> 6);
  if (i >= n) return;
  bool act = lane < OUT_C;
  float di = dinv[i];
  float a = act ? di * z[(size_t)i * OUT_C + lane] : 0.f;
  int e = rowptr[i], end = rowptr[i + 1];
  for (; e + 3 < end; e += 4) {
    int s0 = csr[e], s1 = csr[e + 1], s2 = csr[e + 2], s3 = csr[e + 3];
    if (act) {
      float a0 = dinv[s0] * z[(size_t)s0 * OUT_C + lane];
      float a1 = dinv[s1] * z[(size_t)s1 * OUT_C + lane];
      float a2 = dinv[s2] * z[(size_t)s2 * OUT_C + lane];
      float a3 = dinv[s3] * z[(size_t)s3 * OUT_C + lane];
      a += (a0 + a1) + (a2 + a3);
    }
  }
  for (; e < end; ++e) {
    int s = csr[e];
    if (act) a += dinv[s] * z[(size_t)s * OUT_C + lane];
  }
  float o = act ? di * a + b2[lane] : -INFINITY;
  float m = o;
  for (int off = 32; off; off >>= 1) m = fmaxf(m, __shfl_xor(m, off));
  float ex = act ? expf(o - m) : 0.f;
  float s = ex;
  for (int off = 32; off; off >>= 1) s += __shfl_xor(s, off);
  if (act) out[(size_t)i * OUT_C + lane] = o - m - logf(s);
}

extern "C" void kernel_launch(void* const* d_in, const int* in_sizes, int n_in,
                              void* d_out, int out_size, void* d_ws, size_t ws_size,
                              hipStream_t stream) {
  const float* x  = (const float*)d_in[0];
  const int* eidx = (const int*)d_in[1];   // harness delivers integers as int32
  const float* W1 = (const float*)d_in[2];
  const float* b1 = (const float*)d_in[3];
  const float* W2 = (const float*)d_in[4];
  const float* b2 = (const float*)d_in[5];
  float* out = (float*)d_out;

  int n = in_sizes[0] / IN_C;
  int E = in_sizes[1] / 2;

  size_t npad = ((size_t)n + 255) & ~(size_t)255;
  size_t Epad = ((size_t)E + 255) & ~(size_t)255;
  // layout (4-byte units)
  size_t o_dinv   = 0;
  size_t o_deg    = o_dinv + npad;
  size_t o_S      = o_deg + npad;
  size_t o_BS     = o_S + npad;
  size_t o_rowptr = o_BS + 256;
  size_t o_cursor = o_rowptr + npad + 256;
  size_t o_csr    = o_cursor + npad;
  size_t o_bufA   = o_csr + Epad;
  size_t o_bufB   = o_bufA + (size_t)n * HID_C;
  size_t needed   = (o_bufB + (size_t)n * HID_C) * 4;
  if (ws_size < needed) return;  // fail via absmax, not GPU fault

  float* ws  = (float*)d_ws;
  float* dinv = ws + o_dinv;
  int* deg    = (int*)(ws + o_deg);
  int* S      = (int*)(ws + o_S);
  int* BS     = (int*)(ws + o_BS);
  int* rowptr = (int*)(ws + o_rowptr);
  int* cursor = (int*)(ws + o_cursor);
  int* csr    = (int*)(ws + o_csr);
  float* bufA = ws + o_bufA;   // y, then z (stride 40 <= 64)
  float* bufB = ws + o_bufB;   // h

  int nb = (int)((n + 1023) / 1024);   // 98 for n=100k; scan2 supports <=128

  // ---- CSR build (shared by both layers) ----
  zero4_kernel<<<128, 256, 0, stream>>>((int4*)deg, (long long)(npad / 4));
  deg_kernel<<<1024, 256, 0, stream>>>(eidx + E, E, deg);
  dinv_kernel<<<(n + 255) / 256, 256, 0, stream>>>(deg, dinv, n);
  scan1_kernel<<<nb, 256, 0, stream>>>(deg, S, BS, n);
  scan2_kernel<<<1, 128, 0, stream>>>(BS, nb);
  scan3_kernel<<<(n + 255) / 256, 256, 0, stream>>>(S, BS, deg, rowptr, cursor, n);
  fill_kernel<<<1024, 256, 0, stream>>>(eidx, E, cursor, csr);

  // ---- layer 1: y = x@W1 ; h = relu(dinv*(gather(y)+dinv*y) + b1) ----
  gemm1_kernel<<<(n + 31) / 32, 256, 0, stream>>>(x, W1, bufA, n);
  gather64_kernel<<<(n + 3) / 4, 256, 0, stream>>>(bufA, rowptr, csr, dinv, b1,
                                                   bufB, n);

  // ---- layer 2: z = h@W2 ; out = log_softmax(dinv*(gather(z)+dinv*z)+b2) ----
  gemm2_kernel<<<(n + 31) / 32, 256, 0, stream>>>(bufB, W2, bufA, n);
  gather40_kernel<<<(n + 3) / 4, 256, 0, stream>>>(bufA, rowptr, csr, dinv, b2,
                                                   out, n);
}

// Round 5
// 295.377 us; speedup vs baseline: 1.7206x; 1.1413x over previous
//
#include <hip/hip_runtime.h>
#include <math.h>

#define IN_C 128
#define HID_C 64
#define OUT_C 40

__device__ __forceinline__ float readlane_f(float v, int l) {
  return __uint_as_float(__builtin_amdgcn_readlane(__float_as_uint(v), l));
}

// ---- grid-stride int4 zero ----
__global__ void zero4_kernel(int4* __restrict__ p, long long n4) {
  long long i = (long long)blockIdx.x * blockDim.x + threadIdx.x;
  long long stride = (long long)gridDim.x * blockDim.x;
  for (; i < n4; i += stride) p[i] = make_int4(0, 0, 0, 0);
}

// ---- degree: count incoming edges (dst side), int atomics ----
__global__ void deg_kernel(const int* __restrict__ dst, int E,
                           int* __restrict__ deg) {
  int i = blockIdx.x * blockDim.x + threadIdx.x;
  int stride = gridDim.x * blockDim.x;
  for (int e = i; e < E; e += stride) atomicAdd(&deg[dst[e]], 1);
}

// ---- dinv[i] = rsqrt(deg[i] + 1)  (self-loop) ----
__global__ void dinv_kernel(const int* __restrict__ deg,
                            float* __restrict__ dinv, int n) {
  int i = blockIdx.x * blockDim.x + threadIdx.x;
  if (i < n) dinv[i] = rsqrtf((float)deg[i] + 1.0f);
}

// ---- scan stage 1: per-1024-chunk inclusive scan + chunk totals ----
__global__ __launch_bounds__(256) void scan1_kernel(
    const int* __restrict__ deg, int* __restrict__ S, int* __restrict__ BS,
    int n) {
  __shared__ int sums[256];
  int t = threadIdx.x;
  int i0 = blockIdx.x * 1024 + t * 4;
  int v0 = (i0 + 0 < n) ? deg[i0 + 0] : 0;
  int v1 = (i0 + 1 < n) ? deg[i0 + 1] : 0;
  int v2 = (i0 + 2 < n) ? deg[i0 + 2] : 0;
  int v3 = (i0 + 3 < n) ? deg[i0 + 3] : 0;
  v1 += v0; v2 += v1; v3 += v2;
  sums[t] = v3;
  __syncthreads();
  for (int off = 1; off < 256; off <<= 1) {
    int x = (t >= off) ? sums[t - off] : 0;
    __syncthreads();
    sums[t] += x;
    __syncthreads();
  }
  int excl = t ? sums[t - 1] : 0;
  if (i0 + 0 < n) S[i0 + 0] = v0 + excl;
  if (i0 + 1 < n) S[i0 + 1] = v1 + excl;
  if (i0 + 2 < n) S[i0 + 2] = v2 + excl;
  if (i0 + 3 < n) S[i0 + 3] = v3 + excl;
  if (t == 255) BS[blockIdx.x] = sums[255];
}

// ---- scan stage 2: exclusive scan of chunk totals (nb <= 128) ----
__global__ __launch_bounds__(128) void scan2_kernel(int* __restrict__ BS,
                                                    int nb) {
  __shared__ int s[128];
  int t = threadIdx.x;
  s[t] = (t < nb) ? BS[t] : 0;
  __syncthreads();
  for (int off = 1; off < 128; off <<= 1) {
    int x = (t >= off) ? s[t - off] : 0;
    __syncthreads();
    s[t] += x;
    __syncthreads();
  }
  if (t < nb) BS[t] = t ? s[t - 1] : 0;
}

// ---- scan stage 3: rowptr + cursor ----
__global__ void scan3_kernel(const int* __restrict__ S,
                             const int* __restrict__ BS,
                             const int* __restrict__ deg,
                             int* __restrict__ rowptr,
                             int* __restrict__ cursor, int n) {
  int i = blockIdx.x * blockDim.x + threadIdx.x;
  if (i < n) {
    int r = S[i] + BS[i >> 10];      // inclusive prefix = rowptr[i+1]
    rowptr[i + 1] = r;
    cursor[i] = r - deg[i];          // = rowptr[i]
    if (i == 0) rowptr[0] = 0;
  }
}

// ---- CSR fill: bucket src indices by dst ----
__global__ void fill_kernel(const int* __restrict__ eidx, int E,
                            int* __restrict__ cursor, int* __restrict__ csr) {
  int i = blockIdx.x * blockDim.x + threadIdx.x;
  int stride = gridDim.x * blockDim.x;
  for (int e = i; e < E; e += stride) {
    int s = eidx[e];
    int d = eidx[E + e];
    int pos = atomicAdd(&cursor[d], 1);
    csr[pos] = s;
  }
}

// ---- y = x @ W1 (128->64): wave per node, W1 column in 128 VGPRs,
//      x row via uniform scalar loads (readfirstlane) ----
__global__ __launch_bounds__(256, 2) void gemm1_kernel(
    const float* __restrict__ x, const float* __restrict__ W1,
    float* __restrict__ y, int n) {
  int lane = threadIdx.x & 63;
  float w[IN_C];
#pragma unroll
  for (int c = 0; c < IN_C; ++c) w[c] = W1[c * HID_C + lane];
  int wid = (int)((blockIdx.x * blockDim.x + threadIdx.x) >> 6);
  int nw = (int)((gridDim.x * blockDim.x) >> 6);
  for (int ii = wid; ii < n; ii += nw) {
    int i = __builtin_amdgcn_readfirstlane(ii);
    const float* xr = x + (size_t)i * IN_C;   // uniform -> s_load path
    float a0 = 0.f, a1 = 0.f, a2 = 0.f, a3 = 0.f;
#pragma unroll
    for (int c = 0; c < IN_C; c += 4) {
      a0 = fmaf(xr[c + 0], w[c + 0], a0);
      a1 = fmaf(xr[c + 1], w[c + 1], a1);
      a2 = fmaf(xr[c + 2], w[c + 2], a2);
      a3 = fmaf(xr[c + 3], w[c + 3], a3);
    }
    y[(size_t)i * HID_C + lane] = (a0 + a1) + (a2 + a3);
  }
}

// ---- gather64 + bias/ReLU + fused gemm2 (64->40): wave per node ----
__global__ __launch_bounds__(256) void gather_gemm2_kernel(
    const float* __restrict__ y, const int* __restrict__ rowptr,
    const int* __restrict__ csr, const float* __restrict__ dinv,
    const float* __restrict__ b1, const float* __restrict__ W2,
    float* __restrict__ z, int n) {
  int lane = threadIdx.x & 63;
  bool actj = lane < OUT_C;
  float w2[HID_C];
#pragma unroll
  for (int c = 0; c < HID_C; ++c)
    w2[c] = actj ? W2[c * OUT_C + lane] : 0.f;
  float bias = b1[lane];
  int wid = (int)((blockIdx.x * blockDim.x + threadIdx.x) >> 6);
  int nw = (int)((gridDim.x * blockDim.x) >> 6);
  for (int ii = wid; ii < n; ii += nw) {
    int i = __builtin_amdgcn_readfirstlane(ii);
    float di = dinv[i];
    float a = di * y[(size_t)i * HID_C + lane];  // self term
    int e = rowptr[i], end = rowptr[i + 1];
    for (; e + 3 < end; e += 4) {
      int s0 = csr[e], s1 = csr[e + 1], s2 = csr[e + 2], s3 = csr[e + 3];
      float a0 = dinv[s0] * y[(size_t)s0 * HID_C + lane];
      float a1 = dinv[s1] * y[(size_t)s1 * HID_C + lane];
      float a2 = dinv[s2] * y[(size_t)s2 * HID_C + lane];
      float a3 = dinv[s3] * y[(size_t)s3 * HID_C + lane];
      a += (a0 + a1) + (a2 + a3);
    }
    for (; e < end; ++e) {
      int s = csr[e];
      a += dinv[s] * y[(size_t)s * HID_C + lane];
    }
    float hv = di * a + bias;
    hv = hv > 0.f ? hv : 0.f;                 // h row, one value per lane
    // fused z = h @ W2: broadcast h via readlane, W2 column in regs
    float z0 = 0.f, z1 = 0.f;
#pragma unroll
    for (int c = 0; c < HID_C; c += 2) {
      z0 = fmaf(readlane_f(hv, c + 0), w2[c + 0], z0);
      z1 = fmaf(readlane_f(hv, c + 1), w2[c + 1], z1);
    }
    if (actj) z[(size_t)i * OUT_C + lane] = z0 + z1;
  }
}

// ---- gather 40ch + bias + log-softmax: wave per node ----
__global__ __launch_bounds__(256) void gather40_kernel(
    const float* __restrict__ z, const int* __restrict__ rowptr,
    const int* __restrict__ csr, const float* __restrict__ dinv,
    const float* __restrict__ b2, float* __restrict__ out, int n) {
  int lane = threadIdx.x & 63;
  bool act = lane < OUT_C;
  float bias = act ? b2[lane] : 0.f;
  int wid = (int)((blockIdx.x * blockDim.x + threadIdx.x) >> 6);
  int nw = (int)((gridDim.x * blockDim.x) >> 6);
  for (int ii = wid; ii < n; ii += nw) {
    int i = __builtin_amdgcn_readfirstlane(ii);
    float di = dinv[i];
    float a = act ? di * z[(size_t)i * OUT_C + lane] : 0.f;
    int e = rowptr[i], end = rowptr[i + 1];
    for (; e + 3 < end; e += 4) {
      int s0 = csr[e], s1 = csr[e + 1], s2 = csr[e + 2], s3 = csr[e + 3];
      if (act) {
        float a0 = dinv[s0] * z[(size_t)s0 * OUT_C + lane];
        float a1 = dinv[s1] * z[(size_t)s1 * OUT_C + lane];
        float a2 = dinv[s2] * z[(size_t)s2 * OUT_C + lane];
        float a3 = dinv[s3] * z[(size_t)s3 * OUT_C + lane];
        a += (a0 + a1) + (a2 + a3);
      }
    }
    for (; e < end; ++e) {
      int s = csr[e];
      if (act) a += dinv[s] * z[(size_t)s * OUT_C + lane];
    }
    float o = act ? di * a + bias : -INFINITY;
    float m = o;
    for (int off = 32; off; off >>= 1) m = fmaxf(m, __shfl_xor(m, off));
    float ex = act ? expf(o - m) : 0.f;
    float s = ex;
    for (int off = 32; off; off >>= 1) s += __shfl_xor(s, off);
    if (act) out[(size_t)i * OUT_C + lane] = o - m - logf(s);
  }
}

extern "C" void kernel_launch(void* const* d_in, const int* in_sizes, int n_in,
                              void* d_out, int out_size, void* d_ws, size_t ws_size,
                              hipStream_t stream) {
  const float* x  = (const float*)d_in[0];
  const int* eidx = (const int*)d_in[1];   // harness delivers integers as int32
  const float* W1 = (const float*)d_in[2];
  const float* b1 = (const float*)d_in[3];
  const float* W2 = (const float*)d_in[4];
  const float* b2 = (const float*)d_in[5];
  float* out = (float*)d_out;

  int n = in_sizes[0] / IN_C;
  int E = in_sizes[1] / 2;

  size_t npad = ((size_t)n + 255) & ~(size_t)255;
  size_t Epad = ((size_t)E + 255) & ~(size_t)255;
  // layout (4-byte units)
  size_t o_dinv   = 0;
  size_t o_deg    = o_dinv + npad;
  size_t o_S      = o_deg + npad;
  size_t o_BS     = o_S + npad;
  size_t o_rowptr = o_BS + 256;
  size_t o_cursor = o_rowptr + npad + 256;
  size_t o_csr    = o_cursor + npad;
  size_t o_bufA   = o_csr + Epad;
  size_t o_bufB   = o_bufA + (size_t)n * HID_C;
  size_t needed   = (o_bufB + (size_t)n * HID_C) * 4;
  if (ws_size < needed) return;  // fail via absmax, not GPU fault

  float* ws  = (float*)d_ws;
  float* dinv = ws + o_dinv;
  int* deg    = (int*)(ws + o_deg);
  int* S      = (int*)(ws + o_S);
  int* BS     = (int*)(ws + o_BS);
  int* rowptr = (int*)(ws + o_rowptr);
  int* cursor = (int*)(ws + o_cursor);
  int* csr    = (int*)(ws + o_csr);
  float* bufA = ws + o_bufA;   // y (n x 64)
  float* bufB = ws + o_bufB;   // z (n x 40)

  int nb = (int)((n + 1023) / 1024);   // 98 for n=100k; scan2 supports <=128

  // ---- CSR build (shared by both layers) ----
  zero4_kernel<<<128, 256, 0, stream>>>((int4*)deg, (long long)(npad / 4));
  deg_kernel<<<1024, 256, 0, stream>>>(eidx + E, E, deg);
  dinv_kernel<<<(n + 255) / 256, 256, 0, stream>>>(deg, dinv, n);
  scan1_kernel<<<nb, 256, 0, stream>>>(deg, S, BS, n);
  scan2_kernel<<<1, 128, 0, stream>>>(BS, nb);
  scan3_kernel<<<(n + 255) / 256, 256, 0, stream>>>(S, BS, deg, rowptr, cursor, n);
  fill_kernel<<<1024, 256, 0, stream>>>(eidx, E, cursor, csr);

  // ---- layer 1 GEMM: y = x @ W1 ----
  gemm1_kernel<<<512, 256, 0, stream>>>(x, W1, bufA, n);
  // ---- gather(y) + bias/ReLU + z = h @ W2 (fused) ----
  gather_gemm2_kernel<<<1024, 256, 0, stream>>>(bufA, rowptr, csr, dinv, b1,
                                                W2, bufB, n);
  // ---- gather(z) + bias + log-softmax ----
  gather40_kernel<<<1024, 256, 0, stream>>>(bufB, rowptr, csr, dinv, b2, out, n);
}